// Round 3
// baseline (895.950 us; speedup 1.0000x reference)
//
#include <hip/hip_runtime.h>
#include <hip/hip_cooperative_groups.h>
#include <cstddef>
#include <cstdint>

namespace cg = cooperative_groups;

#define H 128
#define EDIM 16
#define NLAYER 3
#define NSLICE 18            // 16 edge_W slices + edge_b + root_W
#define WCOLS (NSLICE * H)   // 2304
#define PCOLS (EDIM * H)     // 2048 bf16 cols of P

typedef unsigned short ushort_t;
typedef unsigned int uint_t;
typedef __attribute__((ext_vector_type(8))) short bf16x8;
typedef __attribute__((ext_vector_type(4))) float f32x4;

__device__ __forceinline__ ushort_t f2bf(float f) {
    uint_t u = __builtin_bit_cast(uint_t, f);
    u += 0x7fffu + ((u >> 16) & 1u);   // RNE
    return (ushort_t)(u >> 16);
}
__device__ __forceinline__ float bf_lo(uint_t u) {
    return __builtin_bit_cast(float, u << 16);
}
__device__ __forceinline__ float bf_hi(uint_t u) {
    return __builtin_bit_cast(float, u & 0xffff0000u);
}

struct Params {
    const float* x; const int* src; const int* dst; const float* eattr; const int* batch;
    const float* nW; const float* nb;
    const float* eW; const float* eb; const float* rW;
    const float* conv_b; const float* gamma; const float* beta;
    const float* W1; const float* b1; const float* W2; const float* b2;
    float* out;
    int* hist; float* cntG; float* bnS; float* bnQ;
    float* agg; float* hA; float* hB; float* xnew;
    ushort_t* Wt; ushort_t* Pb; float* QR;
    float* zbase; int zcount;
    int N, E, G;
};

union SMem {
    struct { ushort_t As[64][136]; ushort_t Bs[64][136]; float sc[H]; float sh[H]; } gemm; // 35840 B
    ushort_t wtile[128][136];                                                             // 34816 B
    struct { float As[16][68]; float Bs[16][68]; } emb;                                   // 8704 B
    struct { float sS[H]; float sQ[H]; } ns;                                              // 1024 B
    struct { float sc[H]; float sh[H]; float part[H]; float pooled[H]; } cls;             // 2048 B
};

// ---------------- P1 helpers ----------------
__device__ void weight_prep(const Params& p, SMem& sm, int b, int t)
{
    const int l = b / NSLICE, s = b % NSLICE;
    const float* S = (s < 16) ? (p.eW + ((size_t)l * 16 + s) * (H * H))
                   : (s == 16 ? (p.eb + (size_t)l * H * H)
                              : (p.rW + (size_t)l * H * H));
    const int k = t >> 1, o0 = (t & 1) * 64;
#pragma unroll
    for (int j = 0; j < 64; j += 4) {
        float4 v = *(const float4*)&S[(size_t)k * H + o0 + j];
        sm.wtile[k][o0 + j + 0] = f2bf(v.x);
        sm.wtile[k][o0 + j + 1] = f2bf(v.y);
        sm.wtile[k][o0 + j + 2] = f2bf(v.z);
        sm.wtile[k][o0 + j + 3] = f2bf(v.w);
    }
    __syncthreads();
    const int n = t >> 1, k0 = (t & 1) * 64;
    ushort_t* outp = p.Wt + ((size_t)l * WCOLS + s * H + n) * H + k0;
#pragma unroll 8
    for (int j = 0; j < 64; ++j) outp[j] = sm.wtile[k0 + j][n];
}

__device__ void embed_gemm(const Params& p, SMem& sm, int b2, int t)
{
    // h = x @ node_W + node_b  (M=N=2048, K=32, Ncols=128), 64x64 tiles
    const int bm = (b2 >> 1) * 64;
    const int bn = (b2 & 1) * 64;
    const int tx = t & 15, ty = t >> 4;
    float acc[4][4];
#pragma unroll
    for (int i = 0; i < 4; ++i)
#pragma unroll
        for (int j = 0; j < 4; ++j) acc[i][j] = 0.f;

    const int ka = t & 15, ma = t >> 4;
    const int nb2 = t & 63, kb = t >> 6;

    for (int k0 = 0; k0 < 32; k0 += 16) {
#pragma unroll
        for (int r = 0; r < 4; ++r)
            sm.emb.As[ka][ma + 16 * r] = p.x[(size_t)(bm + ma + 16 * r) * 32 + k0 + ka];
#pragma unroll
        for (int r = 0; r < 4; ++r)
            sm.emb.Bs[kb + 4 * r][nb2] = p.nW[(size_t)(k0 + kb + 4 * r) * H + bn + nb2];
        __syncthreads();
#pragma unroll
        for (int kk = 0; kk < 16; ++kk) {
            const float4 a4 = *(const float4*)&sm.emb.As[kk][ty * 4];
            const float4 b4 = *(const float4*)&sm.emb.Bs[kk][tx * 4];
            const float a[4] = {a4.x, a4.y, a4.z, a4.w};
            const float b[4] = {b4.x, b4.y, b4.z, b4.w};
#pragma unroll
            for (int i = 0; i < 4; ++i)
#pragma unroll
                for (int j = 0; j < 4; ++j)
                    acc[i][j] = fmaf(a[i], b[j], acc[i][j]);
        }
        __syncthreads();
    }
#pragma unroll
    for (int i = 0; i < 4; ++i) {
        const int row = bm + ty * 4 + i;
        float4 v;
        v.x = acc[i][0] + p.nb[bn + tx * 4 + 0];
        v.y = acc[i][1] + p.nb[bn + tx * 4 + 1];
        v.z = acc[i][2] + p.nb[bn + tx * 4 + 2];
        v.w = acc[i][3] + p.nb[bn + tx * 4 + 3];
        *(float4*)&p.hA[(size_t)row * H + bn + tx * 4] = v;
    }
}

// ---------------- per-layer phases ----------------
__device__ void gemm_phase(const Params& p, SMem& sm, int l, int bid, int tid, int NB)
{
    const int ncb = WCOLS / 64;                  // 36 col blocks
    const int ntiles = ncb * (p.N / 64);         // 1152
    const float* hsrc = (l == 2) ? p.hB : p.hA;  // l==0,1 read hA; l==2 reads hB
    float* hdst = (l == 1) ? p.hB : ((l == 2) ? p.hA : nullptr);
    if (l > 0 && tid < H) {
        const int ls = l - 1;
        const float invN = 1.0f / (float)p.N;
        const float mu = p.bnS[ls * H + tid] * invN;
        const float var = p.bnQ[ls * H + tid] * invN - mu * mu;
        const float s_ = rsqrtf(var + 1e-5f) * p.gamma[ls * H + tid];
        sm.gemm.sc[tid] = s_;
        sm.gemm.sh[tid] = p.beta[ls * H + tid] - mu * s_;
    }
    for (int tt = bid; tt < ntiles; tt += NB) {
        __syncthreads();                         // LDS reuse + sc/sh ready
        const int i = tt % ncb, j = tt / ncb;
        const int n0 = i * 64, v0 = j * 64;
        const int row = tid >> 2, col0 = (tid & 3) * 32;
        {   // stage B (bf16 weights, k-contiguous)
            const ushort_t* gb = p.Wt + ((size_t)l * WCOLS + n0 + row) * H + col0;
#pragma unroll
            for (int jj = 0; jj < 32; jj += 8)
                *(uint4*)&sm.gemm.Bs[row][col0 + jj] = *(const uint4*)(gb + jj);
        }
        {   // stage A (fp32 h, optional fused BN+ReLU+residual of prev layer)
            const float* ga = hsrc + (size_t)(v0 + row) * H + col0;
            if (l == 0) {
#pragma unroll
                for (int jj = 0; jj < 32; jj += 4) {
                    const float4 v = *(const float4*)(ga + jj);
                    uint2 u;
                    u.x = (uint_t)f2bf(v.x) | ((uint_t)f2bf(v.y) << 16);
                    u.y = (uint_t)f2bf(v.z) | ((uint_t)f2bf(v.w) << 16);
                    *(uint2*)&sm.gemm.As[row][col0 + jj] = u;
                }
            } else {
                const float* gx = p.xnew + (size_t)(v0 + row) * H + col0;
                float* gh = hdst + (size_t)(v0 + row) * H + col0;
#pragma unroll
                for (int jj = 0; jj < 32; jj += 4) {
                    const float4 hv = *(const float4*)(ga + jj);
                    const float4 xv = *(const float4*)(gx + jj);
                    const float4 scv = *(const float4*)&sm.gemm.sc[col0 + jj];
                    const float4 shv = *(const float4*)&sm.gemm.sh[col0 + jj];
                    float4 hn;
                    hn.x = hv.x + fmaxf(xv.x * scv.x + shv.x, 0.f);
                    hn.y = hv.y + fmaxf(xv.y * scv.y + shv.y, 0.f);
                    hn.z = hv.z + fmaxf(xv.z * scv.z + shv.z, 0.f);
                    hn.w = hv.w + fmaxf(xv.w * scv.w + shv.w, 0.f);
                    if (i == 0) *(float4*)(gh + jj) = hn;   // materialize h_l once
                    uint2 u;
                    u.x = (uint_t)f2bf(hn.x) | ((uint_t)f2bf(hn.y) << 16);
                    u.y = (uint_t)f2bf(hn.z) | ((uint_t)f2bf(hn.w) << 16);
                    *(uint2*)&sm.gemm.As[row][col0 + jj] = u;
                }
            }
        }
        __syncthreads();

        const int wave = tid >> 6, lane = tid & 63;
        const int l15 = lane & 15, kg = lane >> 4;
        const int mrow = wave * 16 + l15;
        f32x4 acc0 = {0.f, 0.f, 0.f, 0.f};
        f32x4 acc1 = {0.f, 0.f, 0.f, 0.f};
        f32x4 acc2 = {0.f, 0.f, 0.f, 0.f};
        f32x4 acc3 = {0.f, 0.f, 0.f, 0.f};
#pragma unroll
        for (int s2 = 0; s2 < 4; ++s2) {
            const int k = s2 * 32 + kg * 8;
            bf16x8 a  = *(const bf16x8*)&sm.gemm.As[mrow][k];
            bf16x8 b0 = *(const bf16x8*)&sm.gemm.Bs[0 * 16 + l15][k];
            bf16x8 b1 = *(const bf16x8*)&sm.gemm.Bs[1 * 16 + l15][k];
            bf16x8 b2 = *(const bf16x8*)&sm.gemm.Bs[2 * 16 + l15][k];
            bf16x8 b3 = *(const bf16x8*)&sm.gemm.Bs[3 * 16 + l15][k];
            acc0 = __builtin_amdgcn_mfma_f32_16x16x32_bf16(a, b0, acc0, 0, 0, 0);
            acc1 = __builtin_amdgcn_mfma_f32_16x16x32_bf16(a, b1, acc1, 0, 0, 0);
            acc2 = __builtin_amdgcn_mfma_f32_16x16x32_bf16(a, b2, acc2, 0, 0, 0);
            acc3 = __builtin_amdgcn_mfma_f32_16x16x32_bf16(a, b3, acc3, 0, 0, 0);
        }
        // D: col = lane&15, row = (lane>>4)*4 + reg
        const int slice = n0 >> 7;
        const int lo = n0 & 127;
        const int row0 = v0 + wave * 16 + kg * 4;
        if (slice < 16) {
            ushort_t* op = p.Pb + (size_t)row0 * PCOLS + slice * H + lo + l15;
#pragma unroll
            for (int r = 0; r < 4; ++r) {
                op[(size_t)r * PCOLS + 0]  = f2bf(acc0[r]);
                op[(size_t)r * PCOLS + 16] = f2bf(acc1[r]);
                op[(size_t)r * PCOLS + 32] = f2bf(acc2[r]);
                op[(size_t)r * PCOLS + 48] = f2bf(acc3[r]);
            }
        } else {
            float* op = p.QR + (size_t)row0 * 256 + (slice - 16) * H + lo + l15;
#pragma unroll
            for (int r = 0; r < 4; ++r) {
                op[(size_t)r * 256 + 0]  = acc0[r];
                op[(size_t)r * 256 + 16] = acc1[r];
                op[(size_t)r * 256 + 32] = acc2[r];
                op[(size_t)r * 256 + 48] = acc3[r];
            }
        }
    }
}

__device__ void edge_phase(const Params& p, int bid, int tid, int NB)
{
    const int wv = tid >> 6, lane = tid & 63;
    for (int e = bid * 4 + wv; e < p.E; e += NB * 4) {
        const int s  = p.src[e];
        const int dv = p.dst[e];
        const float* eap = p.eattr + (size_t)e * EDIM;
        const float4 w0 = *(const float4*)(eap + 0);
        const float4 w1 = *(const float4*)(eap + 4);
        const float4 w2 = *(const float4*)(eap + 8);
        const float4 w3 = *(const float4*)(eap + 12);
        const float w[16] = {w0.x, w0.y, w0.z, w0.w, w1.x, w1.y, w1.z, w1.w,
                             w2.x, w2.y, w2.z, w2.w, w3.x, w3.y, w3.z, w3.w};
        const uint_t* prow = (const uint_t*)p.Pb + (size_t)s * (PCOLS / 2) + lane;
        const float2 q2 = *(const float2*)(p.QR + (size_t)s * 256 + 2 * lane);
        float m0 = q2.x, m1 = q2.y;
#pragma unroll
        for (int d = 0; d < EDIM; ++d) {
            const uint_t u = prow[(size_t)d * 64];
            m0 = fmaf(w[d], bf_lo(u), m0);
            m1 = fmaf(w[d], bf_hi(u), m1);
        }
        atomicAdd(&p.agg[(size_t)dv * H + 2 * lane], m0);
        atomicAdd(&p.agg[(size_t)dv * H + 2 * lane + 1], m1);
    }
}

__device__ void nodestats_phase(const Params& p, SMem& sm, int l, int bid, int tid, int NB)
{
    const int ngroups = p.N / 8;
    const int c = tid & 127, half = tid >> 7;
    const float cb = p.conv_b[l * H + c];
    for (int vg = bid; vg < ngroups; vg += NB) {
        const int v0 = vg * 8 + half * 4;
        float s = 0.f, q = 0.f;
#pragma unroll
        for (int j = 0; j < 4; ++j) {
            const int v = v0 + j;
            const int deg = p.hist[v];
            const float rc = 1.0f / (float)(deg > 0 ? deg : 1);
            const size_t ix = (size_t)v * H + c;
            const float val = p.agg[ix] * rc + p.QR[(size_t)v * 256 + H + c] + cb;
            p.xnew[ix] = val;
            p.agg[ix] = 0.f;                 // ready for next layer
            s += val;
            q += val * val;
        }
        if (half == 0) { sm.ns.sS[c] = s; sm.ns.sQ[c] = q; }
        __syncthreads();
        if (half == 1) {
            atomicAdd(&p.bnS[l * H + c], sm.ns.sS[c] + s);
            atomicAdd(&p.bnQ[l * H + c], sm.ns.sQ[c] + q);
        }
        __syncthreads();
    }
}

__device__ void classifier_phase(const Params& p, SMem& sm, int bid, int tid)
{
    if (bid >= p.G) return;
    const int g = bid;
    const int c = tid & 127, half = tid >> 7;
    if (tid < H) {   // BN scale/shift for layer 2
        const float invN = 1.0f / (float)p.N;
        const float mu = p.bnS[2 * H + tid] * invN;
        const float var = p.bnQ[2 * H + tid] * invN - mu * mu;
        const float s_ = rsqrtf(var + 1e-5f) * p.gamma[2 * H + tid];
        sm.cls.sc[tid] = s_;
        sm.cls.sh[tid] = p.beta[2 * H + tid] - mu * s_;
    }
    __syncthreads();
    // node range of graph g (batch is sorted): prefix over cntG
    int lo = 0;
    for (int i = 0; i < g; ++i) lo += (int)p.cntG[i];
    const int cnt = (int)p.cntG[g];
    float s = 0.f;
    for (int v = lo + half; v < lo + cnt; v += 2) {
        const size_t ix = (size_t)v * H + c;
        s += p.hA[ix] + fmaxf(p.xnew[ix] * sm.cls.sc[c] + sm.cls.sh[c], 0.f);
    }
    if (half == 0) sm.cls.part[c] = s;
    __syncthreads();
    if (half == 1) sm.cls.pooled[c] = (sm.cls.part[c] + s) / fmaxf((float)cnt, 1.0f);
    __syncthreads();
    if (tid < 64) {
        float acc = p.b1[tid];
#pragma unroll 8
        for (int i = 0; i < H; ++i)
            acc = fmaf(sm.cls.pooled[i], p.W1[i * 64 + tid], acc);
        float pv = fmaxf(acc, 0.f) * p.W2[tid];
#pragma unroll
        for (int off = 32; off > 0; off >>= 1)
            pv += __shfl_down(pv, off);
        if (tid == 0) p.out[g] = pv + p.b2[0];
    }
}

// ---------------- the mega kernel ----------------
__global__ __launch_bounds__(256, 4) void mega_kernel(Params p)
{
    __shared__ SMem sm;
    cg::grid_group grid = cg::this_grid();
    const int tid = threadIdx.x;
    const int bid = blockIdx.x;
    const int NB  = gridDim.x;

    // P0: zero workspace accumulators
    for (int i = bid * 256 + tid; i < p.zcount; i += NB * 256) p.zbase[i] = 0.f;
    grid.sync();

    // P1: histograms + weight transpose + node-embed GEMM
    for (int g = bid * 256 + tid; g < p.E; g += NB * 256) atomicAdd(&p.hist[p.dst[g]], 1);
    for (int g = bid * 256 + tid; g < p.N; g += NB * 256) atomicAdd(&p.cntG[p.batch[g]], 1.f);
    if (bid < NLAYER * NSLICE)                       weight_prep(p, sm, bid, tid);
    else if (bid < NLAYER * NSLICE + (p.N / 32))     embed_gemm(p, sm, bid - NLAYER * NSLICE, tid);
    grid.sync();

    for (int l = 0; l < NLAYER; ++l) {
        gemm_phase(p, sm, l, bid, tid, NB);
        grid.sync();
        edge_phase(p, bid, tid, NB);
        grid.sync();
        nodestats_phase(p, sm, l, bid, tid, NB);
        grid.sync();
    }
    classifier_phase(p, sm, bid, tid);
}

extern "C" void kernel_launch(void* const* d_in, const int* in_sizes, int n_in,
                              void* d_out, int out_size, void* d_ws, size_t ws_size,
                              hipStream_t stream)
{
    const int N = in_sizes[0] / 32;   // 2048
    const int E = in_sizes[1] / 2;    // 8192
    const int G = out_size;           // 128

    // ---- workspace layout (16B aligned) ----
    int* hist   = (int*)d_ws;                         // N
    float* cntG = (float*)(hist + N);                 // G
    float* bnS  = cntG + G;                           // 3*H
    float* bnQ  = bnS + NLAYER * H;                   // 3*H
    float* agg  = bnQ + NLAYER * H;                   // N*H
    // --- end of zero region ---
    float* hA   = agg + (size_t)N * H;                // N*H
    float* hB   = hA + (size_t)N * H;                 // N*H
    float* xnew = hB + (size_t)N * H;                 // N*H
    ushort_t* Wt = (ushort_t*)(xnew + (size_t)N * H); // 3*WCOLS*H
    ushort_t* Pb = Wt + (size_t)NLAYER * WCOLS * H;   // N*PCOLS
    float* QR   = (float*)(Pb + (size_t)N * PCOLS);   // N*256

    Params P;
    P.x = (const float*)d_in[0];
    P.src = (const int*)d_in[1];
    P.dst = ((const int*)d_in[1]) + E;
    P.eattr = (const float*)d_in[2];
    P.batch = (const int*)d_in[3];
    P.nW = (const float*)d_in[4];  P.nb = (const float*)d_in[5];
    P.eW = (const float*)d_in[6];  P.eb = (const float*)d_in[7];
    P.rW = (const float*)d_in[8];  P.conv_b = (const float*)d_in[9];
    P.gamma = (const float*)d_in[10]; P.beta = (const float*)d_in[11];
    P.W1 = (const float*)d_in[12]; P.b1 = (const float*)d_in[13];
    P.W2 = (const float*)d_in[14]; P.b2 = (const float*)d_in[15];
    P.out = (float*)d_out;
    P.hist = hist; P.cntG = cntG; P.bnS = bnS; P.bnQ = bnQ;
    P.agg = agg; P.hA = hA; P.hB = hB; P.xnew = xnew;
    P.Wt = Wt; P.Pb = Pb; P.QR = QR;
    P.zbase = (float*)d_ws;
    P.zcount = N + G + 2 * NLAYER * H + N * H;        // hist..agg (ints zero as 0.f bits)
    P.N = N; P.E = E; P.G = G;

    // grid size: co-resident blocks (static-cached occupancy query)
    static int gblocks = 0;
    if (gblocks == 0) {
        int dev = 0;
        (void)hipGetDevice(&dev);
        int cus = 256;
        if (hipDeviceGetAttribute(&cus, hipDeviceAttributeMultiprocessorCount, dev)
            != hipSuccess || cus < 1) cus = 256;
        int nb = 0;
        if (hipOccupancyMaxActiveBlocksPerMultiprocessor(&nb, mega_kernel, 256, 0)
            != hipSuccess || nb < 1) nb = 2;
        long long t = (long long)nb * cus;
        if (t > 1024) t = 1024;
        if (t < 256) t = 256;
        gblocks = (int)t;
    }

    void* kargs[] = {(void*)&P};
    (void)hipLaunchCooperativeKernel(mega_kernel, dim3(gblocks), dim3(256),
                                     kargs, 0, stream);
}

// Round 4
// 229.215 us; speedup vs baseline: 3.9088x; 3.9088x over previous
//
#include <hip/hip_runtime.h>
#include <cstddef>
#include <cstdint>

#define H 128
#define EDIM 16
#define NLAYER 3
#define NSLICE 18            // 16 edge_W slices + edge_b + root_W
#define WCOLS (NSLICE * H)   // 2304
#define PCOLS (EDIM * H)     // 2048 bf16 cols of P

typedef unsigned short ushort_t;
typedef unsigned int uint_t;
typedef __attribute__((ext_vector_type(8))) short bf16x8;
typedef __attribute__((ext_vector_type(4))) float f32x4;

__device__ __forceinline__ ushort_t f2bf(float f) {
    uint_t u = __builtin_bit_cast(uint_t, f);
    u += 0x7fffu + ((u >> 16) & 1u);   // RNE
    return (ushort_t)(u >> 16);
}
__device__ __forceinline__ float bf_lo(uint_t u) {
    return __builtin_bit_cast(float, u << 16);
}
__device__ __forceinline__ float bf_hi(uint_t u) {
    return __builtin_bit_cast(float, u & 0xffff0000u);
}

// ---- setup: blocks 0..31 histograms, 32..85 weight prep, 86..149 embed GEMM
__global__ __launch_bounds__(256) void setup_kernel(
    const int* __restrict__ dst, const int* __restrict__ batch,
    int* __restrict__ histD, float* __restrict__ cntG, int E, int N,
    const float* __restrict__ eW, const float* __restrict__ eb,
    const float* __restrict__ rW, ushort_t* __restrict__ Wt,
    const float* __restrict__ x, const float* __restrict__ nW,
    const float* __restrict__ nbias, float* __restrict__ hA)
{
    __shared__ alignas(16) ushort_t tile[128][136];
    const int t = threadIdx.x;

    if (blockIdx.x < 32) {
        const int g = blockIdx.x * 256 + t;
        if (g < E) atomicAdd(&histD[dst[g]], 1);
        if (g < N) atomicAdd(&cntG[batch[g]], 1.f);
        return;
    }

    if (blockIdx.x < 86) {
        // weight prep: fp32 [k][o] slice -> bf16 Wt[l][n][k]
        const int b = blockIdx.x - 32;       // 0..53
        const int l = b / NSLICE, s = b % NSLICE;
        const float* S = (s < 16) ? (eW + ((size_t)l * 16 + s) * (H * H))
                       : (s == 16 ? (eb + (size_t)l * H * H)
                                  : (rW + (size_t)l * H * H));
        const int k = t >> 1, o0 = (t & 1) * 64;
#pragma unroll
        for (int j = 0; j < 64; j += 4) {
            float4 v = *(const float4*)&S[(size_t)k * H + o0 + j];
            tile[k][o0 + j + 0] = f2bf(v.x);
            tile[k][o0 + j + 1] = f2bf(v.y);
            tile[k][o0 + j + 2] = f2bf(v.z);
            tile[k][o0 + j + 3] = f2bf(v.w);
        }
        __syncthreads();
        const int n = t >> 1, k0 = (t & 1) * 64;
        ushort_t* outp = Wt + ((size_t)l * WCOLS + s * H + n) * H + k0;
#pragma unroll 8
        for (int j = 0; j < 64; ++j) outp[j] = tile[k0 + j][n];
        return;
    }

    // ---- node-embed GEMM: hA = x @ node_W + node_b (M=2048,K=32,N=128) ----
    const int b2 = blockIdx.x - 86;          // 0..63
    const int bm = (b2 >> 1) * 64;
    const int bn = (b2 & 1) * 64;
    float (*As)[68] = (float (*)[68])(void*)tile;        // 16x68 f32
    float (*Bs)[68] = ((float (*)[68])(void*)tile) + 16; // next 16x68 f32

    const int tx = t & 15, ty = t >> 4;
    float acc[4][4];
#pragma unroll
    for (int i = 0; i < 4; ++i)
#pragma unroll
        for (int j = 0; j < 4; ++j) acc[i][j] = 0.f;

    const int ka = t & 15, ma = t >> 4;
    const int nb2 = t & 63, kb = t >> 6;

    for (int k0 = 0; k0 < 32; k0 += 16) {
#pragma unroll
        for (int r = 0; r < 4; ++r)
            As[ka][ma + 16 * r] = x[(size_t)(bm + ma + 16 * r) * 32 + k0 + ka];
#pragma unroll
        for (int r = 0; r < 4; ++r)
            Bs[kb + 4 * r][nb2] = nW[(size_t)(k0 + kb + 4 * r) * H + bn + nb2];
        __syncthreads();
#pragma unroll
        for (int kk = 0; kk < 16; ++kk) {
            const float4 a4 = *(const float4*)&As[kk][ty * 4];
            const float4 b4 = *(const float4*)&Bs[kk][tx * 4];
            const float a[4] = {a4.x, a4.y, a4.z, a4.w};
            const float b[4] = {b4.x, b4.y, b4.z, b4.w};
#pragma unroll
            for (int i = 0; i < 4; ++i)
#pragma unroll
                for (int j = 0; j < 4; ++j)
                    acc[i][j] = fmaf(a[i], b[j], acc[i][j]);
        }
        __syncthreads();
    }
#pragma unroll
    for (int i = 0; i < 4; ++i) {
        const int row = bm + ty * 4 + i;
        float4 v;
        v.x = acc[i][0] + nbias[bn + tx * 4 + 0];
        v.y = acc[i][1] + nbias[bn + tx * 4 + 1];
        v.z = acc[i][2] + nbias[bn + tx * 4 + 2];
        v.w = acc[i][3] + nbias[bn + tx * 4 + 3];
        *(float4*)&hA[(size_t)row * H + bn + tx * 4] = v;
    }
}

// ---- bf16 MFMA GEMM, with fused BN+ReLU+residual of the PREVIOUS layer ----
// A-row = fuse ? (hsrc + relu(xnew*sc+sh)) : hsrc ; materialized to hdst once.
__global__ __launch_bounds__(256) void mfma_gemm(
    const float* __restrict__ hsrc, const float* __restrict__ xnew,
    float* __restrict__ hdst, const ushort_t* __restrict__ Wt,
    ushort_t* __restrict__ Pb, float* __restrict__ QR,
    const float* __restrict__ bnS, const float* __restrict__ bnQ,
    const float* __restrict__ gamma, const float* __restrict__ beta,
    int N, int fuse)
{
    __shared__ ushort_t As[64][136];
    __shared__ ushort_t Bs[64][136];
    __shared__ float sc[H], sh[H];
    const int tid = threadIdx.x;
    const int n0 = blockIdx.x * 64;
    const int v0 = blockIdx.y * 64;

    if (fuse) {
        if (tid < H) {
            const float invN = 1.0f / (float)N;
            const float mu = bnS[tid] * invN;
            const float var = bnQ[tid] * invN - mu * mu;
            const float s_ = rsqrtf(var + 1e-5f) * gamma[tid];
            sc[tid] = s_;
            sh[tid] = beta[tid] - mu * s_;
        }
        __syncthreads();
    }

    const int row = tid >> 2, col0 = (tid & 3) * 32;
    {   // stage B (bf16 weights, k-contiguous)
        const ushort_t* gb = Wt + (size_t)(n0 + row) * H + col0;
#pragma unroll
        for (int jj = 0; jj < 32; jj += 8)
            *(uint4*)&Bs[row][col0 + jj] = *(const uint4*)(gb + jj);
    }
    {   // stage A
        const float* ga = hsrc + (size_t)(v0 + row) * H + col0;
        if (!fuse) {
#pragma unroll
            for (int jj = 0; jj < 32; jj += 4) {
                const float4 v = *(const float4*)(ga + jj);
                uint2 u;
                u.x = (uint_t)f2bf(v.x) | ((uint_t)f2bf(v.y) << 16);
                u.y = (uint_t)f2bf(v.z) | ((uint_t)f2bf(v.w) << 16);
                *(uint2*)&As[row][col0 + jj] = u;
            }
        } else {
            const float* gx = xnew + (size_t)(v0 + row) * H + col0;
            float* gh = hdst + (size_t)(v0 + row) * H + col0;
#pragma unroll
            for (int jj = 0; jj < 32; jj += 4) {
                const float4 hv = *(const float4*)(ga + jj);
                const float4 xv = *(const float4*)(gx + jj);
                const float4 scv = *(const float4*)&sc[col0 + jj];
                const float4 shv = *(const float4*)&sh[col0 + jj];
                float4 hn;
                hn.x = hv.x + fmaxf(xv.x * scv.x + shv.x, 0.f);
                hn.y = hv.y + fmaxf(xv.y * scv.y + shv.y, 0.f);
                hn.z = hv.z + fmaxf(xv.z * scv.z + shv.z, 0.f);
                hn.w = hv.w + fmaxf(xv.w * scv.w + shv.w, 0.f);
                if (blockIdx.x == 0) *(float4*)(gh + jj) = hn;  // h_l once
                uint2 u;
                u.x = (uint_t)f2bf(hn.x) | ((uint_t)f2bf(hn.y) << 16);
                u.y = (uint_t)f2bf(hn.z) | ((uint_t)f2bf(hn.w) << 16);
                *(uint2*)&As[row][col0 + jj] = u;
            }
        }
    }
    __syncthreads();

    const int wave = tid >> 6, lane = tid & 63;
    const int l15 = lane & 15, kg = lane >> 4;
    const int mrow = wave * 16 + l15;
    f32x4 acc0 = {0.f, 0.f, 0.f, 0.f};
    f32x4 acc1 = {0.f, 0.f, 0.f, 0.f};
    f32x4 acc2 = {0.f, 0.f, 0.f, 0.f};
    f32x4 acc3 = {0.f, 0.f, 0.f, 0.f};
#pragma unroll
    for (int s2 = 0; s2 < 4; ++s2) {
        const int k = s2 * 32 + kg * 8;
        bf16x8 a  = *(const bf16x8*)&As[mrow][k];
        bf16x8 b0 = *(const bf16x8*)&Bs[0 * 16 + l15][k];
        bf16x8 b1 = *(const bf16x8*)&Bs[1 * 16 + l15][k];
        bf16x8 b2 = *(const bf16x8*)&Bs[2 * 16 + l15][k];
        bf16x8 b3 = *(const bf16x8*)&Bs[3 * 16 + l15][k];
        acc0 = __builtin_amdgcn_mfma_f32_16x16x32_bf16(a, b0, acc0, 0, 0, 0);
        acc1 = __builtin_amdgcn_mfma_f32_16x16x32_bf16(a, b1, acc1, 0, 0, 0);
        acc2 = __builtin_amdgcn_mfma_f32_16x16x32_bf16(a, b2, acc2, 0, 0, 0);
        acc3 = __builtin_amdgcn_mfma_f32_16x16x32_bf16(a, b3, acc3, 0, 0, 0);
    }
    // D: col = lane&15, row = (lane>>4)*4 + reg
    const int slice = n0 >> 7;
    const int lo = n0 & 127;
    const int row0 = v0 + wave * 16 + kg * 4;
    if (slice < 16) {
        ushort_t* op = Pb + (size_t)row0 * PCOLS + slice * H + lo + l15;
#pragma unroll
        for (int r = 0; r < 4; ++r) {
            op[(size_t)r * PCOLS + 0]  = f2bf(acc0[r]);
            op[(size_t)r * PCOLS + 16] = f2bf(acc1[r]);
            op[(size_t)r * PCOLS + 32] = f2bf(acc2[r]);
            op[(size_t)r * PCOLS + 48] = f2bf(acc3[r]);
        }
    } else {
        float* op = QR + (size_t)row0 * 256 + (slice - 16) * H + lo + l15;
#pragma unroll
        for (int r = 0; r < 4; ++r) {
            op[(size_t)r * 256 + 0]  = acc0[r];
            op[(size_t)r * 256 + 16] = acc1[r];
            op[(size_t)r * 256 + 32] = acc2[r];
            op[(size_t)r * 256 + 48] = acc3[r];
        }
    }
}

// ---- edge-parallel message + atomic scatter-add into agg -------------------
__global__ __launch_bounds__(256) void edge_msg(
    const ushort_t* __restrict__ Pb, const float* __restrict__ QR,
    const float* __restrict__ ea, const int* __restrict__ srcArr,
    const int* __restrict__ dstArr, float* __restrict__ agg, int E)
{
    const int wave = threadIdx.x >> 6, lane = threadIdx.x & 63;
    const int e = blockIdx.x * 4 + wave;
    if (e >= E) return;
    const int s  = srcArr[e];
    const int dv = dstArr[e];
    const float* eap = ea + (size_t)e * EDIM;
    const float4 w0 = *(const float4*)(eap + 0);
    const float4 w1 = *(const float4*)(eap + 4);
    const float4 w2 = *(const float4*)(eap + 8);
    const float4 w3 = *(const float4*)(eap + 12);
    const float w[16] = {w0.x, w0.y, w0.z, w0.w, w1.x, w1.y, w1.z, w1.w,
                         w2.x, w2.y, w2.z, w2.w, w3.x, w3.y, w3.z, w3.w};
    const uint_t* prow = (const uint_t*)Pb + (size_t)s * (PCOLS / 2) + lane;
    const float2 q2 = *(const float2*)(QR + (size_t)s * 256 + 2 * lane);
    float m0 = q2.x, m1 = q2.y;
#pragma unroll
    for (int d = 0; d < EDIM; ++d) {
        const uint_t u = prow[(size_t)d * 64];
        m0 = fmaf(w[d], bf_lo(u), m0);
        m1 = fmaf(w[d], bf_hi(u), m1);
    }
    atomicAdd(&agg[(size_t)dv * H + 2 * lane], m0);
    atomicAdd(&agg[(size_t)dv * H + 2 * lane + 1], m1);
}

// ---- per-node finish: xnew = agg/deg + root + bias; BN stats; re-zero agg -
__global__ __launch_bounds__(256) void node_stats(
    float* __restrict__ agg, const float* __restrict__ QR,
    const int* __restrict__ histD, const float* __restrict__ conv_b,
    float* __restrict__ xnew, float* __restrict__ bnS, float* __restrict__ bnQ)
{
    __shared__ float sS[H];
    __shared__ float sQ[H];
    const int tid = threadIdx.x;
    const int c = tid & 127, half = tid >> 7;
    const int v0 = blockIdx.x * 8 + half * 4;
    const float cb = conv_b[c];
    float s = 0.f, q = 0.f;
#pragma unroll
    for (int j = 0; j < 4; ++j) {
        const int v = v0 + j;
        const int deg = histD[v];
        const float rc = 1.0f / (float)(deg > 0 ? deg : 1);
        const size_t ix = (size_t)v * H + c;
        const float val = agg[ix] * rc + QR[(size_t)v * 256 + H + c] + cb;
        xnew[ix] = val;
        agg[ix] = 0.f;                       // ready for next layer
        s += val;
        q += val * val;
    }
    if (half == 0) { sS[c] = s; sQ[c] = q; }
    __syncthreads();
    if (half == 1) {
        atomicAdd(&bnS[c], sS[c] + s);
        atomicAdd(&bnQ[c], sQ[c] + q);
    }
}

// ---- classifier: fused BN(l2)+ReLU+residual + mean-pool + MLP -------------
__global__ __launch_bounds__(256) void classifier_kernel(
    const float* __restrict__ h2, const float* __restrict__ xnew,
    const float* __restrict__ bnS, const float* __restrict__ bnQ,
    const float* __restrict__ gamma, const float* __restrict__ beta,
    const float* __restrict__ cntG,
    const float* __restrict__ W1, const float* __restrict__ b1,
    const float* __restrict__ W2, const float* __restrict__ b2,
    float* __restrict__ out, int N)
{
    __shared__ float sc[H], sh[H], part[H], pooled[H];
    const int g = blockIdx.x;
    const int tid = threadIdx.x;
    const int c = tid & 127, half = tid >> 7;
    if (tid < H) {
        const float invN = 1.0f / (float)N;
        const float mu = bnS[tid] * invN;
        const float var = bnQ[tid] * invN - mu * mu;
        const float s_ = rsqrtf(var + 1e-5f) * gamma[tid];
        sc[tid] = s_;
        sh[tid] = beta[tid] - mu * s_;
    }
    __syncthreads();
    // node range of graph g (batch is sorted): prefix over cntG
    int lo = 0;
    for (int i = 0; i < g; ++i) lo += (int)cntG[i];
    const int cnt = (int)cntG[g];
    float s = 0.f;
    for (int v = lo + half; v < lo + cnt; v += 2) {
        const size_t ix = (size_t)v * H + c;
        s += h2[ix] + fmaxf(xnew[ix] * sc[c] + sh[c], 0.f);
    }
    if (half == 0) part[c] = s;
    __syncthreads();
    if (half == 1) pooled[c] = (part[c] + s) / fmaxf((float)cnt, 1.0f);
    __syncthreads();
    if (tid < 64) {
        float acc = b1[tid];
#pragma unroll 8
        for (int i = 0; i < H; ++i)
            acc = fmaf(pooled[i], W1[i * 64 + tid], acc);
        float pv = fmaxf(acc, 0.f) * W2[tid];
#pragma unroll
        for (int off = 32; off > 0; off >>= 1)
            pv += __shfl_down(pv, off);
        if (tid == 0) out[g] = pv + b2[0];
    }
}

extern "C" void kernel_launch(void* const* d_in, const int* in_sizes, int n_in,
                              void* d_out, int out_size, void* d_ws, size_t ws_size,
                              hipStream_t stream)
{
    const float* x      = (const float*)d_in[0];
    const int*   eidx   = (const int*)  d_in[1];
    const float* eattr  = (const float*)d_in[2];
    const int*   batch  = (const int*)  d_in[3];
    const float* node_W = (const float*)d_in[4];
    const float* node_b = (const float*)d_in[5];
    const float* edge_W = (const float*)d_in[6];
    const float* edge_b = (const float*)d_in[7];
    const float* root_W = (const float*)d_in[8];
    const float* conv_b = (const float*)d_in[9];
    const float* gamma  = (const float*)d_in[10];
    const float* beta   = (const float*)d_in[11];
    const float* W1     = (const float*)d_in[12];
    const float* b1     = (const float*)d_in[13];
    const float* W2     = (const float*)d_in[14];
    const float* b2     = (const float*)d_in[15];
    float* out = (float*)d_out;

    const int N = in_sizes[0] / 32;   // 2048
    const int E = in_sizes[1] / 2;    // 8192
    const int G = out_size;           // 128

    // ---- workspace layout (16B aligned) ----
    int* histD  = (int*)d_ws;                         // N
    float* cntG = (float*)(histD + N);                // G
    float* bnS  = cntG + G;                           // 3*H
    float* bnQ  = bnS + NLAYER * H;                   // 3*H
    float* agg  = bnQ + NLAYER * H;                   // N*H
    // --- end of zero region ---
    float* hA   = agg + (size_t)N * H;                // N*H
    float* hB   = hA + (size_t)N * H;                 // N*H
    float* xnew = hB + (size_t)N * H;                 // N*H
    ushort_t* Wt = (ushort_t*)(xnew + (size_t)N * H); // 3*WCOLS*H
    ushort_t* Pb = Wt + (size_t)NLAYER * WCOLS * H;   // N*PCOLS
    float* QR   = (float*)(Pb + (size_t)N * PCOLS);   // N*256

    const size_t zbytes = ((size_t)N + G + 2 * NLAYER * H + (size_t)N * H) * 4;
    hipMemsetAsync(d_ws, 0, zbytes, stream);

    const int* src = eidx;
    const int* dst = eidx + E;

    setup_kernel<<<150, 256, 0, stream>>>(
        dst, batch, histD, cntG, E, N, edge_W, edge_b, root_W, Wt,
        x, node_W, node_b, hA);

    // layer l: hsrc/hdst ping-pong.  l0: src=hA (no fuse).
    // l1: src=hA + xnew0 -> hB.  l2: src=hB + xnew1 -> hA.
    const float* hsrc[NLAYER] = { hA, hA, hB };
    float*       hdst[NLAYER] = { nullptr, hB, hA };

    for (int l = 0; l < NLAYER; ++l) {
        mfma_gemm<<<dim3(WCOLS / 64, N / 64), 256, 0, stream>>>(
            hsrc[l], xnew, hdst[l], Wt + (size_t)l * WCOLS * H, Pb, QR,
            bnS + (size_t)(l - 1) * H, bnQ + (size_t)(l - 1) * H,
            gamma + (size_t)(l - 1) * H, beta + (size_t)(l - 1) * H,
            N, l > 0);
        edge_msg<<<E / 4, 256, 0, stream>>>(
            Pb, QR, eattr, src, dst, agg, E);
        node_stats<<<N / 8, 256, 0, stream>>>(
            agg, QR, histD, conv_b + (size_t)l * H,
            xnew, bnS + l * H, bnQ + l * H);
    }

    // classifier pools h2 + relu(bn2(xnew2)) directly (batch sorted)
    classifier_kernel<<<G, 256, 0, stream>>>(
        hA, xnew, bnS + 2 * H, bnQ + 2 * H, gamma + 2 * H, beta + 2 * H,
        cntG, W1, b1, W2, b2, out, N);
}